// Round 14
// baseline (1522.706 us; speedup 1.0000x reference)
//
#include <hip/hip_runtime.h>

#define SEQ  4096
#define HID  128
#define BT   2            // real batch columns per block (replicated into 16 MFMA cols)
#define NBLK (256 / BT)   // 128 blocks, 256 threads each -> 1 wave per SIMD

typedef int   i32x4 __attribute__((ext_vector_type(4)));
typedef float f32x4 __attribute__((ext_vector_type(4)));

#define L2E  1.44269504088896340736f   // log2(e)
#define L2E2 2.88539008177792681472f   // 2*log2(e)

__device__ __forceinline__ float exp2_(float x) { return __builtin_amdgcn_exp2f(x); }
__device__ __forceinline__ float rcp_(float x)  { return __builtin_amdgcn_rcpf(x); }
// gate pre-scaled by log2e: sigmoid(x) = 1/(1+2^-x')
__device__ __forceinline__ float sigm2(float xp) { return rcp_(1.f + exp2_(-xp)); }
// gate pre-scaled by 2*log2e: tanh(x) = 1 - 2/(1+2^x')
__device__ __forceinline__ float tanh2(float xp) { return 1.f - 2.f * rcp_(1.f + exp2_(xp)); }

// One block = 2 batch columns, 4 waves (256 thr) -> ONE wave per SIMD.
// Round 14 = round 10 (best: 1461us) with ONE change: wf (input-proj weights,
// 16 VGPR) and dq (dequant scales, 4 VGPR) parked in LDS and re-read each step
// (5 conflict-free lane-linear ds_read_b128, issued in the latency shadow,
// consumed last). Rationale: r10/r13 spill is structural (persistent live set
// ~150 > 128-cap) and survives any unroll; r11/r12 proved UNCAPPING costs
// ~230cy via worse scheduling. Shrinking the persistent set keeps the good
// (256,2) schedule AND removes the in-loop scratch round-trip.
__global__ __launch_bounds__(256, 2)
void lstm_mfma(const float* __restrict__ inputs,   // (B,S,3)
               const float* __restrict__ hx0,      // (B,128)
               const float* __restrict__ cx0,      // (B,128)
               const float* __restrict__ W_inp,    // (64,3)
               const float* __restrict__ b_inp,    // (64)
               const float* __restrict__ W_ih,     // (512,64)
               const float* __restrict__ b_ih,     // (512)
               const float* __restrict__ W_hh,     // (512,128)
               const float* __restrict__ b_hh,     // (512)
               const float* __restrict__ W_out,    // (40,128)
               const float* __restrict__ b_out,    // (40)
               float*       __restrict__ out)      // (B,40)
{
    // h state (int8), double-buffered, transposed:
    // byte (kt,q,c,i) = h_q[k = kt*64 + q*16 + i][col c]
    __shared__ signed char xvT[2][2][4][2][16];   // 512 B
    // input ring (f32): slot s&15 holds {u0,u1,u2,pad} per col, filled 8+ ahead
    __shared__ float uring[16][2][4];             // 512 B
    __shared__ float hxf[BT][HID + 4];            // final fp32 hx for out-projection
    // parked per-lane constants (read back every step; lane-linear, conflict-free)
    __shared__ float wfl[4][256][4];              // 16 KB: input-proj weights
    __shared__ float dql[256][4];                 //  4 KB: dequant scales

    const int tid  = threadIdx.x;
    const int w    = tid >> 6;        // wave 0..3 (one per SIMD)
    const int lane = tid & 63;
    const int q    = lane >> 4;       // 0..3
    const int n    = lane & 15;
    const int bbase = blockIdx.x * BT;

    const int  cc   = n & 1;                 // lane's batch column
    const bool rb1  = (n >> 1) & 1;          // acc reg select bit 0
    const bool rb2  = (n >> 2) & 1;          // acc reg select bit 1
    const bool hi8  = (n >> 3) & 1;          // M-subtile select
    const int  rr   = (n >> 1) & 3;
    const int  hrow = w * 16 + (hi8 ? 64 : 0) + q * 4 + rr;  // lane's hidden row

    // ---- A fragments: int8, per-row symmetric scale, 2 M-subtiles per gate ------
    // Lane (q,n), gate t, subtile s, K-tile kt holds W_hh[m][kt*64 + q*16 + i],
    // m = t*128 + (w + 4s)*16 + n. A and B share the slot->k bijection (verified).
    i32x4 A[4][2][2];
    #pragma unroll
    for (int t = 0; t < 4; ++t) {
        #pragma unroll
        for (int s = 0; s < 2; ++s) {
            const int m = t * 128 + (w + 4 * s) * 16 + n;
            const float* whr = W_hh + m * HID;
            float mx = 0.f;
            for (int k = 0; k < 128; ++k) mx = fmaxf(mx, fabsf(whr[k]));
            const float rs = (mx > 0.f) ? 127.f / mx : 0.f;
            #pragma unroll
            for (int kt = 0; kt < 2; ++kt) {
                union { signed char c[16]; i32x4 v; } pk;
                #pragma unroll
                for (int i = 0; i < 16; ++i)
                    pk.c[i] = (signed char)(int)rintf(whr[kt * 64 + q * 16 + i] * rs);
                A[t][s][kt] = pk.v;
            }
        }
        // epilogue row me = t*128 + hrow: scale recomputed identically by every
        // lane that touches row me (deterministic fp -> consistent with A-quant);
        // parked in LDS (per-lane slot, re-read each step)
        const int me = t * 128 + hrow;
        const float* whe = W_hh + me * HID;
        float mxe = 0.f;
        for (int k = 0; k < 128; ++k) mxe = fmaxf(mxe, fabsf(whe[k]));
        dql[tid][t] = (mxe / 127.f) * (1.f / 127.f) * ((t == 2) ? L2E2 : L2E);
    }

    // ---- weff for THIS lane's epilogue row -> parked in LDS ---------------------
    #pragma unroll
    for (int t = 0; t < 4; ++t) {
        const float scl = (t == 2) ? L2E2 : L2E;
        const int m2 = t * 128 + hrow;
        const float* wir = W_ih + m2 * 64;
        float wx = 0.f, wy = 0.f, wz = 0.f, bb = 0.f;
        for (int hh = 0; hh < 64; ++hh) {
            float wv = wir[hh];
            wx += wv * W_inp[hh * 3 + 0];
            wy += wv * W_inp[hh * 3 + 1];
            wz += wv * W_inp[hh * 3 + 2];
            bb += wv * b_inp[hh];
        }
        bb += b_ih[m2] + b_hh[m2];
        wfl[t][tid][0] = wx * scl;
        wfl[t][tid][1] = wy * scl;
        wfl[t][tid][2] = wz * scl;
        wfl[t][tid][3] = bb * scl;
    }

    // ---- Loader lane mapping (wave 1): 48 floats = 8 steps x 2 cols x 3 ---------
    const bool uldr = (w == 1) && (lane < 48);
    const int  col0 = lane / 24, rem0 = lane % 24, slot0 = rem0 / 3, wi0 = rem0 % 3;
    const float* up0 = inputs + (size_t)(bbase + col0) * (SEQ * 3) + wi0;

    // ---- Init LDS ----------------------------------------------------------------
    if (tid < 2 * 2 * 4 * 2 * 16 / 4) ((int*)xvT)[tid] = 0;
    __syncthreads();
    {   // h0 quantized (clip to [-1,1]: only perturbs step 1, damped by forget gate)
        int c = tid >> 7, h = tid & 127;
        float v = hx0[(bbase + c) * HID + h];
        v = fminf(fmaxf(v, -1.f), 1.f);
        xvT[0][h >> 6][(h >> 4) & 3][c][h & 15] = (signed char)(int)rintf(v * 127.f);
    }
    if (uldr) {   // ring slots 0..15 = steps 0..15
        uring[slot0][col0][wi0]     = up0[slot0 * 3];
        uring[8 + slot0][col0][wi0] = up0[(8 + slot0) * 3];
    }
    float creg = cx0[(bbase + cc) * HID + hrow];
    __syncthreads();

    float pend0 = 0.f, hl = 0.f;

    // ---- Recurrent loop: 16 statically-unrolled substeps per iteration -----------
    for (int sb = 0; sb < SEQ; sb += 16) {
        #pragma unroll
        for (int j = 0; j < 16; ++j) {
            signed char (*br)[4][2][16] = xvT[j & 1];
            signed char (*bw)[4][2][16] = xvT[(j + 1) & 1];

            // deep input prefetch: issue at j=0/8 (8+ steps ahead), write at j=4/12
            if (uldr) {
                if (j == 0) {
                    int st0 = sb + 8 + slot0; if (st0 > SEQ - 1) st0 = SEQ - 1;
                    pend0 = up0[st0 * 3];
                } else if (j == 4) {        // slots 8..15 <- steps sb+8..sb+15
                    uring[8 + slot0][col0][wi0] = pend0;
                } else if (j == 8) {
                    int st0 = sb + 16 + slot0; if (st0 > SEQ - 1) st0 = SEQ - 1;
                    pend0 = up0[st0 * 3];
                } else if (j == 12) {       // slots 0..7 <- steps sb+16..sb+23
                    uring[slot0][col0][wi0] = pend0;
                }
            }

            // LDS reads, in consumption order: B first (MFMA), then u, then the
            // parked constants (consumed last, deepest in the shadow).
            const i32x4 B0 = *reinterpret_cast<const i32x4*>(&br[0][q][cc][0]);
            const i32x4 B1 = *reinterpret_cast<const i32x4*>(&br[1][q][cc][0]);
            const f32x4 u4 = *reinterpret_cast<const f32x4*>(&uring[j][cc][0]);
            const f32x4 wf0 = *reinterpret_cast<const f32x4*>(&wfl[0][tid][0]);
            const f32x4 wf1 = *reinterpret_cast<const f32x4*>(&wfl[1][tid][0]);
            const f32x4 wf2 = *reinterpret_cast<const f32x4*>(&wfl[2][tid][0]);
            const f32x4 wf3 = *reinterpret_cast<const f32x4*>(&wfl[3][tid][0]);
            const f32x4 dqv = *reinterpret_cast<const f32x4*>(&dql[tid][0]);

            // input projection (exact f32, independent of MFMA results)
            float inp[4];
            inp[0] = fmaf(wf0[0], u4[0], fmaf(wf0[1], u4[1], fmaf(wf0[2], u4[2], wf0[3])));
            inp[1] = fmaf(wf1[0], u4[0], fmaf(wf1[1], u4[1], fmaf(wf1[2], u4[2], wf1[3])));
            inp[2] = fmaf(wf2[0], u4[0], fmaf(wf2[1], u4[1], fmaf(wf2[2], u4[2], wf2[3])));
            inp[3] = fmaf(wf3[0], u4[0], fmaf(wf3[1], u4[1], fmaf(wf3[2], u4[2], wf3[3])));

            const i32x4 z4 = {0, 0, 0, 0};
            // per-gate: 4 MFMAs (2 subtiles x 2 K) then 1-of-8 select + activation;
            // activation VALU/TRANS hides under the next gate's MFMA drain.
            float gv4[4];
            #pragma unroll
            for (int t = 0; t < 4; ++t) {
                i32x4 a0 = __builtin_amdgcn_mfma_i32_16x16x64_i8(A[t][0][0], B0, z4, 0, 0, 0);
                a0       = __builtin_amdgcn_mfma_i32_16x16x64_i8(A[t][0][1], B1, a0, 0, 0, 0);
                i32x4 a1 = __builtin_amdgcn_mfma_i32_16x16x64_i8(A[t][1][0], B0, z4, 0, 0, 0);
                a1       = __builtin_amdgcn_mfma_i32_16x16x64_i8(A[t][1][1], B1, a1, 0, 0, 0);
                int s0 = rb1 ? a0[1] : a0[0];
                int s1 = rb1 ? a0[3] : a0[2];
                int v0 = rb2 ? s1 : s0;
                int t0 = rb1 ? a1[1] : a1[0];
                int t1 = rb1 ? a1[3] : a1[2];
                int v1 = rb2 ? t1 : t0;
                int v  = hi8 ? v1 : v0;
                gv4[t] = (float)v * dqv[t] + inp[t];
            }

            // one LSTM update per lane (fp32 state); all exp are exp2
            float iv = sigm2(gv4[0]), fv = sigm2(gv4[1]);
            float gg = tanh2(gv4[2]), ov = sigm2(gv4[3]);
            creg = fv * creg + iv * gg;
            float th = tanh2(creg * L2E2);
            float h  = ov * th;                       // |h| < 1 by construction
            hl = h;

            bw[hi8 ? 1 : 0][w][cc][q * 4 + rr] = (signed char)(int)rintf(h * 127.f);
            __syncthreads();
        }
    }

    // ---- Out projection: out[b] = W_out @ hx_last + b_out (f32 h, unquantized) ---
    hxf[cc][hrow] = hl;
    __syncthreads();
    if (tid < BT * 40) {
        int bl = tid / 40, o = tid % 40;
        const float* wr = W_out + o * HID;
        float a = b_out[o];
        #pragma unroll 8
        for (int k = 0; k < HID; ++k) a += wr[k] * hxf[bl][k];
        out[(bbase + bl) * 40 + o] = a;
    }
}

extern "C" void kernel_launch(void* const* d_in, const int* in_sizes, int n_in,
                              void* d_out, int out_size, void* d_ws, size_t ws_size,
                              hipStream_t stream) {
    const float* inputs = (const float*)d_in[0];
    const float* hx0    = (const float*)d_in[1];
    const float* cx0    = (const float*)d_in[2];
    const float* W_inp  = (const float*)d_in[3];
    const float* b_inp  = (const float*)d_in[4];
    const float* W_ih   = (const float*)d_in[5];
    const float* b_ih   = (const float*)d_in[6];
    const float* W_hh   = (const float*)d_in[7];
    const float* b_hh   = (const float*)d_in[8];
    const float* W_out  = (const float*)d_in[9];
    const float* b_out  = (const float*)d_in[10];
    float* out = (float*)d_out;

    lstm_mfma<<<NBLK, 256, 0, stream>>>(inputs, hx0, cx0, W_inp, b_inp, W_ih, b_ih,
                                        W_hh, b_hh, W_out, b_out, out);
}